// Round 17
// baseline (249.019 us; speedup 1.0000x reference)
//
#include <hip/hip_runtime.h>
#include <hip/hip_fp16.h>

#define N0 50000
#define N1 100000
#define N2 25000
#define E00 200000
#define E11 200000
#define E10 100000
#define E21 50000
#define EE  550000   // E00+E10+E11+E21 (concatenated edge space)
#define ND  300000   // 50000(u00)+50000(b10)+100000(u11)+100000(b21) dst slots
#define NB  293      // ceil(ND/1024) scan blocks
#define NT_ALL 18750 // ND/16 semantic tiles
#define HID 128
#define INC 64
#define CNT_BLKS 2149  // ceil(EE/256) edge-count blocks (in proj's launch)

typedef _Float16 half8 __attribute__((ext_vector_type(8)));
typedef _Float16 half4_t __attribute__((ext_vector_type(4)));
typedef float float4v __attribute__((ext_vector_type(4)));
typedef float floatx2 __attribute__((ext_vector_type(2)));

__device__ __forceinline__ void decode_edge(
    int e, const int* ei00, const int* ei10, const int* ei11, const int* ei21,
    int& src, int& slot)
{
    if (e < E00)                    { src = ei00[e];               slot = ei00[E00 + e]; }
    else if (e < E00 + E10)         { int i = e - E00;             src = ei10[i]; slot = 50000  + ei10[E10 + i]; }
    else if (e < E00 + E10 + E11)   { int i = e - E00 - E10;       src = ei11[i]; slot = 100000 + ei11[E11 + i]; }
    else                            { int i = e - E00 - E10 - E11; src = ei21[i]; slot = 200000 + ei21[E21 + i]; }
}

// ---------------------------------------------------------------------------
// Kernel A: prep v2 — WEIGHTS ONLY (32 blocks, ~3 us).
// ---------------------------------------------------------------------------
struct PrepT {
    const float* W; const float* bias;
    const float* av0; const float* av1; const float* av2; const float* av3;
    _Float16* wtg; _Float16* adtg; float* bdc;
};

__global__ __launch_bounds__(256) void prep_kernel(
    PrepT p0, PrepT p1, PrepT p2,
    const float* __restrict__ kw, const float* __restrict__ lw,
    unsigned char* __restrict__ kwf8)
{
    if (blockIdx.x >= 24) {
        int base = (blockIdx.x - 24) * 256 + threadIdx.x;
        for (int it = 0; it < 9; ++it) {
            int idx = base + it * 2048;
            int f = idx >> 7, g = idx & 127;
            float v;
            if (f < 128)      v = 2.0f * kw[g * 128 + f];   // pre-scale by 2 (exact)
            else if (f < 130) v = lw[g * 2 + (f - 128)];
            else              v = 0.f;
            int r = __builtin_amdgcn_cvt_pk_fp8_f32(v, 0.f, 0, false);
            kwf8[idx] = (unsigned char)r;
        }
        return;
    }
    PrepT P = (blockIdx.x >= 16) ? p2 : (blockIdx.x >= 8) ? p1 : p0;
    const int lb = blockIdx.x & 7;
    const int t2 = lb * 256 + threadIdx.x;   // 0..2047
    {
        int f = t2 >> 4, g0 = (t2 & 15) * 4;
        half4_t v;
#pragma unroll
        for (int j = 0; j < 4; ++j) v[j] = (_Float16)P.W[(g0 + j) * 128 + f];
        *(half4_t*)&P.wtg[f * 64 + g0] = v;
    }
    {
        int c = t2 >> 6, g = t2 & 63;
        const float* av = (c < 8) ? P.av0 : (c < 16) ? P.av1 : (c < 24) ? P.av2 : P.av3;
        float v = 0.f;
        if (av) {
            int hh = c & 7;
#pragma unroll
            for (int d = 0; d < 16; ++d)
                v += P.W[g * 128 + hh * 16 + d] * av[hh * 16 + d];
        }
        P.adtg[c * 64 + g] = (_Float16)v;
    }
    if (lb == 0 && threadIdx.x < 32) {
        int c = threadIdx.x;
        const float* av = (c < 8) ? P.av0 : (c < 16) ? P.av1 : (c < 24) ? P.av2 : P.av3;
        float v = 0.f;
        if (av) {
            int hh = c & 7;
#pragma unroll
            for (int d = 0; d < 16; ++d)
                v += P.bias[hh * 16 + d] * av[hh * 16 + d];
        }
        P.bdc[c] = v;
    }
}

// ---------------------------------------------------------------------------
// Kernel B: proj_mfma v8 (+edge-count fused). The LDS->occupancy model is
// twice-verified (38.9KB/4blk/44us -> 29.8KB/5blk/<40us). Last rung:
// QUARTER repack tile — process nt in 4 groups of 2; ht [4][16][34] = 4.4KB;
// each lane packs 2 fp8 bytes (fi*2, fi*2+1) per row per quarter (2B store,
// 32B contiguous per 16 lanes, L2 write-combines). LDS total ~24.9KB ->
// 6 blocks/CU (+20% waves). VGPR/structure otherwise unchanged from the
// R16-verified v7. Tripwires: VGPR ~52-64, WRITE 48 MB flat.
// ---------------------------------------------------------------------------
struct PT {
    const float* x; const float* bias; unsigned char* h;
    _Float16* ao0; _Float16* ao1; _Float16* ao2; _Float16* ao3;
    const _Float16* wtg; const _Float16* adtg; const float* bdc;
    int N; int ntiles; int bstart; int nblocks;
};

#define PROJ_BLKS 1024

__global__ __launch_bounds__(256) void proj_mfma(
    PT t0, PT t1, PT t2,
    const int* __restrict__ ei00, const int* __restrict__ ei10,
    const int* __restrict__ ei11, const int* __restrict__ ei21,
    int* __restrict__ cnt)
{
    __shared__ _Float16 ht[4][16][34];     // 4.4 KB: per-wave QUARTER h tile
    __shared__ half8 lbs[1280];            // 20 KB: [nt*2+kb][lane] | bd at 1024+
    __shared__ float biasl[128];
    __shared__ float bdcl[32];
    const int tid = threadIdx.x;
    const int lane = tid & 63, wv = tid >> 6;
    const int fi = lane & 15, hi = lane >> 4;

    if (blockIdx.x >= PROJ_BLKS) {
        // edge count: decode + atomic
        int e = (blockIdx.x - PROJ_BLKS) * 256 + tid;
        if (e >= EE) return;
        int src, slot;
        decode_edge(e, ei00, ei10, ei11, ei21, src, slot);
        atomicAdd(&cnt[slot], 1);
        return;
    }

    PT A = (blockIdx.x >= t2.bstart) ? t2 : (blockIdx.x >= t1.bstart) ? t1 : t0;

    const int stride = A.nblocks * 4;
    const int tb = (blockIdx.x - A.bstart) * 4 + wv;

    // ---- issue ALL 3 tiles' x loads up front (in flight across staging) ----
    float4 xa0, xa1, xa2, xa3, xb0, xb1, xb2, xb3, xc0, xc1, xc2, xc3;
#define LOADX(I, U0, U1, U2, U3)                                                \
    {   const int tt = tb + (I) * stride;                                       \
        if (tt < A.ntiles) {                                                    \
            int rsrc = tt * 16 + fi; if (rsrc >= A.N) rsrc = A.N - 1;           \
            const float* xp = A.x + (size_t)rsrc * 64 + hi * 8;                 \
            U0 = *(const float4*)(xp);      U1 = *(const float4*)(xp + 4);      \
            U2 = *(const float4*)(xp + 32); U3 = *(const float4*)(xp + 36);     \
        } }
    LOADX(0, xa0, xa1, xa2, xa3)
    LOADX(1, xb0, xb1, xb2, xb3)
    LOADX(2, xc0, xc1, xc2, xc3)

    // ---- stage B into LDS: entries 0..1023 = bfr[nt][kb], 1024..1279 = bd ----
#pragma unroll
    for (int it = 0; it < 5; ++it) {
        int e = it * 256 + tid;            // 0..1279
        int ln = e & 63;
        int efi = ln & 15, ehi = ln >> 4;
        if (e < 1024) {
            int nt = e >> 7, kb = (e >> 6) & 1;
            lbs[e] = *(const half8*)&A.wtg[(nt * 16 + efi) * 64 + kb * 32 + ehi * 8];
        } else {
            int e2 = e - 1024;
            int t = e2 >> 7, kb = (e2 >> 6) & 1;
            lbs[e] = *(const half8*)&A.adtg[(t * 16 + efi) * 64 + kb * 32 + ehi * 8];
        }
    }
    if (tid < 128)      biasl[tid] = A.bias[tid];
    else if (tid < 160) bdcl[tid - 128] = A.bdc[tid - 128];
    __syncthreads();

    const float bdc0 = bdcl[fi];
    const float bdc1 = bdcl[16 + fi];
    _Float16* aolo = (fi >= 8) ? A.ao1 : A.ao0;
    _Float16* aohi = (fi >= 8) ? A.ao3 : A.ao2;
    const bool has_hi = (A.ao2 != nullptr) || (A.ao3 != nullptr);

#define COMPX(I, U0, U1, U2, U3)                                                \
    {   const int tt = tb + (I) * stride;                                       \
        if (tt < A.ntiles) {                                                    \
            const int base = tt * 16;                                           \
            half8 a0, a1;                                                       \
            a0[0] = (_Float16)U0.x; a0[1] = (_Float16)U0.y;                     \
            a0[2] = (_Float16)U0.z; a0[3] = (_Float16)U0.w;                     \
            a0[4] = (_Float16)U1.x; a0[5] = (_Float16)U1.y;                     \
            a0[6] = (_Float16)U1.z; a0[7] = (_Float16)U1.w;                     \
            a1[0] = (_Float16)U2.x; a1[1] = (_Float16)U2.y;                     \
            a1[2] = (_Float16)U2.z; a1[3] = (_Float16)U2.w;                     \
            a1[4] = (_Float16)U3.x; a1[5] = (_Float16)U3.y;                     \
            a1[6] = (_Float16)U3.z; a1[7] = (_Float16)U3.w;                     \
            _Pragma("unroll 2")                                                 \
            for (int qf = 0; qf < 4; ++qf) {                                    \
                _Pragma("unroll 2")                                             \
                for (int n2 = 0; n2 < 2; ++n2) {                                \
                    int nt = qf * 2 + n2;                                       \
                    half8 b0 = lbs[(nt * 2 + 0) * 64 + lane];                   \
                    half8 b1 = lbs[(nt * 2 + 1) * 64 + lane];                   \
                    float4v z = {0.f, 0.f, 0.f, 0.f};                           \
                    z = __builtin_amdgcn_mfma_f32_16x16x32_f16(a0, b0, z, 0, 0, 0); \
                    z = __builtin_amdgcn_mfma_f32_16x16x32_f16(a1, b1, z, 0, 0, 0); \
                    float bv = biasl[nt * 16 + fi];                             \
                    _Pragma("unroll")                                           \
                    for (int r = 0; r < 4; ++r)                                 \
                        ht[wv][hi * 4 + r][n2 * 16 + fi] = (_Float16)(z[r] + bv); \
                }                                                               \
                _Pragma("unroll")                                               \
                for (int i = 0; i < 4; ++i) {                                   \
                    int row = i * 4 + hi;                                       \
                    int node = base + row;                                      \
                    if (node < A.N) {                                           \
                        float v0 = (float)ht[wv][row][fi * 2 + 0];              \
                        float v1 = (float)ht[wv][row][fi * 2 + 1];              \
                        int pa = __builtin_amdgcn_cvt_pk_fp8_f32(v0, v1, 0, false); \
                        *(short*)(A.h + (size_t)node * 128 + qf * 32 + fi * 2) = (short)pa; \
                    }                                                           \
                }                                                               \
            }                                                                   \
            float4v d0 = {0.f, 0.f, 0.f, 0.f};                                  \
            d0 = __builtin_amdgcn_mfma_f32_16x16x32_f16(a0, lbs[1024 + lane], d0, 0, 0, 0); \
            d0 = __builtin_amdgcn_mfma_f32_16x16x32_f16(a1, lbs[1088 + lane], d0, 0, 0, 0); \
            float4v d1 = {0.f, 0.f, 0.f, 0.f};                                  \
            if (has_hi) {                                                       \
                d1 = __builtin_amdgcn_mfma_f32_16x16x32_f16(a0, lbs[1152 + lane], d1, 0, 0, 0); \
                d1 = __builtin_amdgcn_mfma_f32_16x16x32_f16(a1, lbs[1216 + lane], d1, 0, 0, 0); \
            }                                                                   \
            if (aolo) {                                                         \
                _Pragma("unroll")                                               \
                for (int r = 0; r < 4; ++r) {                                   \
                    int node = base + hi * 4 + r;                               \
                    if (node < A.N) aolo[(size_t)node * 8 + (fi & 7)] = (_Float16)(d0[r] + bdc0); \
                }                                                               \
            }                                                                   \
            if (aohi) {                                                         \
                _Pragma("unroll")                                               \
                for (int r = 0; r < 4; ++r) {                                   \
                    int node = base + hi * 4 + r;                               \
                    if (node < A.N) aohi[(size_t)node * 8 + (fi & 7)] = (_Float16)(d1[r] + bdc1); \
                }                                                               \
            }                                                                   \
        } }
    COMPX(0, xa0, xa1, xa2, xa3)
    COMPX(1, xb0, xb1, xb2, xb3)
    COMPX(2, xc0, xc1, xc2, xc3)
}

// ---------------------------------------------------------------------------
// Kernel C1: scan1 — per-1024-chunk totals of cnt.
// ---------------------------------------------------------------------------
__global__ __launch_bounds__(256) void scan1_kernel(
    const int* __restrict__ cnt, int* __restrict__ part)
{
    __shared__ int swt[4];
    const int tid = threadIdx.x;
    const int b = blockIdx.x;
    int i0 = b * 1024 + tid * 4;
    int s = 0;
#pragma unroll
    for (int k = 0; k < 4; ++k) { int i = i0 + k; s += (i < ND) ? cnt[i] : 0; }
#pragma unroll
    for (int off = 1; off < 64; off <<= 1) s += __shfl_xor(s, off);
    if ((tid & 63) == 0) swt[tid >> 6] = s;
    __syncthreads();
    if (tid == 0) part[b] = swt[0] + swt[1] + swt[2] + swt[3];
}

// ---------------------------------------------------------------------------
// Kernel C2: scan23 — each block replicates the 293-partial exclusive scan
// locally, then does scan3's offset/cursor writes.
// ---------------------------------------------------------------------------
__global__ __launch_bounds__(256) void scan23_kernel(
    const int* __restrict__ cnt, const int* __restrict__ part,
    int* __restrict__ off, int* __restrict__ cursor)
{
    __shared__ int sd[256];
    __shared__ int pex[512];
    __shared__ int wt[4];
    const int tid = threadIdx.x, b = blockIdx.x;
    const int lane = tid & 63, wv = tid >> 6;

    int p0 = (2 * tid     < NB) ? part[2 * tid]     : 0;
    int p1 = (2 * tid + 1 < NB) ? part[2 * tid + 1] : 0;
    int ps = p0 + p1;
    sd[tid] = ps; __syncthreads();
    for (int d = 1; d < 256; d <<= 1) {
        int v = (tid >= d) ? sd[tid - d] : 0;
        __syncthreads();
        sd[tid] += v;
        __syncthreads();
    }
    int exc = sd[tid] - ps;
    pex[2 * tid] = exc;
    pex[2 * tid + 1] = exc + p0;
    __syncthreads();

    int i0 = b * 1024 + tid * 4;
    int v[4];
#pragma unroll
    for (int k = 0; k < 4; ++k) { int i = i0 + k; v[k] = (i < ND) ? cnt[i] : 0; }
    int ts = v[0] + v[1] + v[2] + v[3];
    int inc = ts;
#pragma unroll
    for (int d = 1; d < 64; d <<= 1) {
        int u = __shfl_up(inc, d);
        if (lane >= d) inc += u;
    }
    int wexc = inc - ts;
    if (lane == 63) wt[wv] = inc;
    __syncthreads();
    int wbase = 0;
    for (int w = 0; w < wv; ++w) wbase += wt[w];
    int base = pex[b] + wbase + wexc;
    int pre = 0;
#pragma unroll
    for (int k = 0; k < 4; ++k) {
        int i = i0 + k;
        if (i < ND) { off[i] = base + pre; cursor[i] = base + pre; }
        pre += v[k];
    }
}

// ---------------------------------------------------------------------------
// Fill v2: CSR placement ONLY (decode edge, cursor atomic, 4B srcs scatter).
// ---------------------------------------------------------------------------
__global__ __launch_bounds__(256) void fill_kernel(
    const int* __restrict__ ei00, const int* __restrict__ ei10,
    const int* __restrict__ ei11, const int* __restrict__ ei21,
    int* __restrict__ cursor, int* __restrict__ srcs)
{
    int e = blockIdx.x * 256 + threadIdx.x;
    if (e >= EE) return;
    int src, slot;
    decode_edge(e, ei00, ei10, ei11, ei21, src, slot);
    int pos = atomicAdd(&cursor[slot], 1);
    srcs[pos] = src;
}

// ---------------------------------------------------------------------------
// Gather v5.2: 8 slots/wave, in-loop f16 attention weights, srcs index
// prefetch one pair ahead (removes the L2 hop from the per-iteration chain).
// ---------------------------------------------------------------------------
__global__ __launch_bounds__(256) void gather_kernel(
    const int* __restrict__ cnt, const int* __restrict__ off,
    const int* __restrict__ srcs,
    const unsigned char* __restrict__ h0, const unsigned char* __restrict__ h1,
    const unsigned char* __restrict__ h2,
    const _Float16* __restrict__ as00, const _Float16* __restrict__ ad00,
    const _Float16* __restrict__ as10, const _Float16* __restrict__ ad10,
    const _Float16* __restrict__ as11, const _Float16* __restrict__ ad11,
    const _Float16* __restrict__ as21, const _Float16* __restrict__ ad21,
    unsigned char* __restrict__ agg)
{
    const int gid = blockIdx.x * 256 + threadIdx.x;
    const int lane = gid & 63;
    const int g8 = lane >> 3, sub = lane & 7;
    const int slot = (gid >> 6) * 8 + g8;           // grid sized so slot < ND
    const unsigned char* hs;
    const _Float16* asp;
    float adv;
    if (slot < 50000)       { hs = h0; asp = as00; adv = (float)ad00[(size_t)slot * 8 + sub]; }
    else if (slot < 100000) { hs = h1; asp = as10; adv = (float)ad10[(size_t)(slot - 50000) * 8 + sub]; }
    else if (slot < 200000) { hs = h1; asp = as11; adv = (float)ad11[(size_t)(slot - 100000) * 8 + sub]; }
    else                    { hs = h2; asp = as21; adv = (float)ad21[(size_t)(slot - 200000) * 8 + sub]; }
    const int deg = cnt[slot], st = off[slot];

    int degm = deg;
    degm = max(degm, __shfl_xor(degm, 8));
    degm = max(degm, __shfl_xor(degm, 16));
    degm = max(degm, __shfl_xor(degm, 32));

    float acc[16];
#pragma unroll
    for (int j = 0; j < 16; ++j) acc[j] = 0.f;
    float sw = 0.f;

    // prefetch first pair's indices
    bool a0n = (0 < deg), a1n = (1 < deg);
    int s0n = 0, s1n = 0;
    if (a0n) s0n = srcs[st + 0];
    if (a1n) s1n = srcs[st + 1];

    int i = 0;
    for (; i + 2 <= degm; i += 2) {
        const bool a0 = a0n, a1 = a1n;
        const int s0 = s0n, s1 = s1n;
        // prefetch next pair's indices (off the critical chain)
        a0n = (i + 2 < deg); a1n = (i + 3 < deg);
        if (a0n) s0n = srcs[st + i + 2];
        if (a1n) s1n = srcs[st + i + 3];

        float w0 = 0.f, w1 = 0.f;
        int4 v0 = {0, 0, 0, 0}, v1 = {0, 0, 0, 0};
        if (a0) { float v = (float)asp[(size_t)s0 * 8 + sub] + adv;
                  v = v > 0.f ? v : 0.2f * v;
                  w0 = __expf(v);
                  v0 = *(const int4*)(hs + (size_t)s0 * 128 + sub * 16); }
        if (a1) { float v = (float)asp[(size_t)s1 * 8 + sub] + adv;
                  v = v > 0.f ? v : 0.2f * v;
                  w1 = __expf(v);
                  v1 = *(const int4*)(hs + (size_t)s1 * 128 + sub * 16); }
        const int wa[4] = {v0.x, v0.y, v0.z, v0.w};
        const int wb[4] = {v1.x, v1.y, v1.z, v1.w};
#pragma unroll
        for (int k = 0; k < 4; ++k) {
            floatx2 fa0 = __builtin_amdgcn_cvt_pk_f32_fp8(wa[k], false);
            floatx2 fa1 = __builtin_amdgcn_cvt_pk_f32_fp8(wa[k], true);
            floatx2 fb0 = __builtin_amdgcn_cvt_pk_f32_fp8(wb[k], false);
            floatx2 fb1 = __builtin_amdgcn_cvt_pk_f32_fp8(wb[k], true);
            acc[4 * k + 0] += w0 * fa0.x + w1 * fb0.x;
            acc[4 * k + 1] += w0 * fa0.y + w1 * fb0.y;
            acc[4 * k + 2] += w0 * fa1.x + w1 * fb1.x;
            acc[4 * k + 3] += w0 * fa1.y + w1 * fb1.y;
        }
        sw += w0 + w1;
    }
    if (i < degm) {
        // tail: a0n/s0n already hold index i's guard/value
        float w0 = 0.f;
        int4 v0 = {0, 0, 0, 0};
        if (a0n) { float v = (float)asp[(size_t)s0n * 8 + sub] + adv;
                   v = v > 0.f ? v : 0.2f * v;
                   w0 = __expf(v);
                   v0 = *(const int4*)(hs + (size_t)s0n * 128 + sub * 16); }
        const int wa[4] = {v0.x, v0.y, v0.z, v0.w};
#pragma unroll
        for (int k = 0; k < 4; ++k) {
            floatx2 fa0 = __builtin_amdgcn_cvt_pk_f32_fp8(wa[k], false);
            floatx2 fa1 = __builtin_amdgcn_cvt_pk_f32_fp8(wa[k], true);
            acc[4 * k + 0] += w0 * fa0.x;
            acc[4 * k + 1] += w0 * fa0.y;
            acc[4 * k + 2] += w0 * fa1.x;
            acc[4 * k + 3] += w0 * fa1.y;
        }
        sw += w0;
    }

    float rr = __builtin_amdgcn_rcpf(sw + 1e-16f);
    int4 o;
    int pk[4];
#pragma unroll
    for (int k = 0; k < 4; ++k) {
        float r0 = fmaxf(acc[4 * k + 0] * rr, 0.f);
        float r1 = fmaxf(acc[4 * k + 1] * rr, 0.f);
        float r2 = fmaxf(acc[4 * k + 2] * rr, 0.f);
        float r3 = fmaxf(acc[4 * k + 3] * rr, 0.f);
        int p = __builtin_amdgcn_cvt_pk_fp8_f32(r0, r1, 0, false);
        p = __builtin_amdgcn_cvt_pk_fp8_f32(r2, r3, p, true);
        pk[k] = p;
    }
    o.x = pk[0]; o.y = pk[1]; o.z = pk[2]; o.w = pk[3];
    *(int4*)(agg + (size_t)slot * 128 + sub * 16) = o;
}

// ---------------------------------------------------------------------------
// Semantic v7 (verified R9-R16): v6 structure + full-depth load prefetch.
// (256,4), grid 1024 — verified allocator point; knob closed.
// ---------------------------------------------------------------------------
__global__ __launch_bounds__(256, 4) void semantic_kernel(
    const unsigned char* __restrict__ agg, const unsigned char* __restrict__ kwf8,
    const float* __restrict__ kb, const float* __restrict__ q,
    const float* __restrict__ lb,
    float* __restrict__ cs2, float* __restrict__ score,
    unsigned int* __restrict__ done, float* __restrict__ out)
{
    __shared__ long lbs[2304];     // 18 KB B frags: [g(9)][kk(4)][lane(64)] x 8B
    __shared__ float kbl[128];     // 2*k_b
    __shared__ float qla[128];     // 2*q
    __shared__ float redv[12];
    const int tid = threadIdx.x;
    const int lane = tid & 63, wv = tid >> 6;
    const int fi = lane & 15, hi = lane >> 4;

    if (tid < 12) redv[tid] = 0.f;
    for (int it = 0; it < 9; ++it) {
        int e = it * 256 + tid;            // 0..2303
        int gk = e >> 6, lp = e & 63;
        int gw = gk >> 2, kkw = gk & 3;
        int fiw = lp & 15, hiw = lp >> 4;
        lbs[e] = *(const long*)&kwf8[(gw * 16 + fiw) * 128 + kkw * 32 + hiw * 8];
    }
    if (tid < 128) kbl[tid] = 2.f * kb[tid];
    else           qla[tid - 128] = 2.f * q[tid - 128];

    const int wid = blockIdx.x * 4 + wv;
    const int nw = gridDim.x * 4;          // 4096

    long af0[4], af1[4], af2[4], af3[4], af4[4];
#define LOADT(I, AF)                                                            \
    {   const int tt = wid + (I) * nw;                                          \
        if (tt < NT_ALL) {                                                      \
            const unsigned char* rowp = agg + ((size_t)(tt * 16 + fi) * 128 + hi * 8); \
            AF[0] = *(const long*)(rowp);       AF[1] = *(const long*)(rowp + 32); \
            AF[2] = *(const long*)(rowp + 64);  AF[3] = *(const long*)(rowp + 96); \
        } else { AF[0] = 0; AF[1] = 0; AF[2] = 0; AF[3] = 0; } }
    LOADT(0, af0) LOADT(1, af1) LOADT(2, af2) LOADT(3, af3) LOADT(4, af4)

    __syncthreads();   // staging visible; global loads remain in flight

    float c4q = 0.f;
#pragma unroll
    for (int g = 0; g < 8; ++g) c4q += 2.f * qla[g * 16 + fi];

    const long* lbl = lbs + lane;

    float sc[4] = {0.f, 0.f, 0.f, 0.f};
    float cs[4] = {0.f, 0.f, 0.f, 0.f};

#define COMPT(I, AF)                                                            \
    {   const int tt = wid + (I) * nw;                                          \
        if (tt < NT_ALL) {                                                      \
            const int m = (tt >= 12500) ? 3 : (tt >= 6250) ? 2 : (tt >= 3125) ? 1 : 0; \
            float tn0 = 0.f, tn1 = 0.f, tn2 = 0.f, tn3 = 0.f, tcs = 0.f;        \
            _Pragma("unroll 3")                                                 \
            for (int g = 0; g < 9; ++g) {                                       \
                long b0 = lbl[g * 256 + 0];                                     \
                long b1 = lbl[g * 256 + 64];                                    \
                long b2 = lbl[g * 256 + 128];                                   \
                long b3 = lbl[g * 256 + 192];                                   \
                if (g < 8) {                                                    \
                    float kbg = kbl[g * 16 + fi];                               \
                    float qg  = qla[g * 16 + fi];                               \
                    float4v c = {kbg, kbg, kbg, kbg};                           \
                    c = __builtin_amdgcn_mfma_f32_16x16x32_fp8_fp8(AF[0], b0, c, 0, 0, 0); \
                    c = __builtin_amdgcn_mfma_f32_16x16x32_fp8_fp8(AF[1], b1, c, 0, 0, 0); \
                    c = __builtin_amdgcn_mfma_f32_16x16x32_fp8_fp8(AF[2], b2, c, 0, 0, 0); \
                    c = __builtin_amdgcn_mfma_f32_16x16x32_fp8_fp8(AF[3], b3, c, 0, 0, 0); \
                    float e0 = __expf(c[0]); tn0 += qg * __builtin_amdgcn_rcpf(e0 + 1.f); \
                    float e1 = __expf(c[1]); tn1 += qg * __builtin_amdgcn_rcpf(e1 + 1.f); \
                    float e2 = __expf(c[2]); tn2 += qg * __builtin_amdgcn_rcpf(e2 + 1.f); \
                    float e3 = __expf(c[3]); tn3 += qg * __builtin_amdgcn_rcpf(e3 + 1.f); \
                } else {                                                        \
                    float4v c = {0.f, 0.f, 0.f, 0.f};                           \
                    c = __builtin_amdgcn_mfma_f32_16x16x32_fp8_fp8(AF[0], b0, c, 0, 0, 0); \
                    c = __builtin_amdgcn_mfma_f32_16x16x32_fp8_fp8(AF[1], b1, c, 0, 0, 0); \
                    c = __builtin_amdgcn_mfma_f32_16x16x32_fp8_fp8(AF[2], b2, c, 0, 0, 0); \
                    c = __builtin_amdgcn_mfma_f32_16x16x32_fp8_fp8(AF[3], b3, c, 0, 0, 0); \
                    tcs = c[0] + c[1] + c[2] + c[3];                            \
                }                                                               \
            }                                                                   \
            float tsc = c4q - ((tn0 + tn1) + (tn2 + tn3));                      \
            if (m == 0)      { sc[0] += tsc; cs[0] += tcs; }                    \
            else if (m == 1) { sc[1] += tsc; cs[1] += tcs; }                    \
            else if (m == 2) { sc[2] += tsc; cs[2] += tcs; }                    \
            else             { sc[3] += tsc; cs[3] += tcs; }                    \
        } }
    COMPT(0, af0) COMPT(1, af1) COMPT(2, af2) COMPT(3, af3) COMPT(4, af4)

#pragma unroll
    for (int m = 0; m < 4; ++m) {
        float s = sc[m];
#pragma unroll
        for (int off = 1; off < 64; off <<= 1) s += __shfl_xor(s, off);
        if (lane == 0 && s != 0.f) atomicAdd(&redv[m], s);
        float v = cs[m];
        v += __shfl_xor(v, 16);
        v += __shfl_xor(v, 32);
        if (hi == 0 && fi < 2 && v != 0.f) atomicAdd(&redv[4 + 2 * m + fi], v);
    }
    __syncthreads();
    if (tid < 4)              atomicAdd(&score[tid], redv[tid]);
    if (tid >= 4 && tid < 12) atomicAdd(&cs2[tid - 4], redv[tid]);

    // last-block final epilogue
    __syncthreads();
    if (tid == 0) {
        __threadfence();
        unsigned int old = atomicAdd(done, 1u);
        if (old == gridDim.x - 1) {
            __threadfence();
            float s0 = score[0] / (float)N0;
            float s1 = score[1] / (float)N0;
            float s2 = score[2] / (float)N1;
            float s3 = score[3] / (float)N1;
            float m0 = fmaxf(s0, s1);
            float e0 = __expf(s0 - m0), e1 = __expf(s1 - m0);
            float a0 = e0 / (e0 + e1), a1 = e1 / (e0 + e1);
            float m1 = fmaxf(s2, s3);
            float e2 = __expf(s2 - m1), e3 = __expf(s3 - m1);
            float a2 = e2 / (e2 + e3), a3 = e3 / (e2 + e3);
            float z0 = a0 * cs2[0] + a1 * cs2[2] + a2 * cs2[4] + a3 * cs2[6] + lb[0];
            float z1 = a0 * cs2[1] + a1 * cs2[3] + a2 * cs2[5] + a3 * cs2[7] + lb[1];
            out[0] = 1.f / (1.f + __expf(-z0));
            out[1] = 1.f / (1.f + __expf(-z1));
        }
    }
}

extern "C" void kernel_launch(void* const* d_in, const int* in_sizes, int n_in,
                              void* d_out, int out_size, void* d_ws, size_t ws_size,
                              hipStream_t stream)
{
    const float* x0  = (const float*)d_in[0];
    const float* x1  = (const float*)d_in[1];
    const float* x2  = (const float*)d_in[2];
    const int* ei00  = (const int*)d_in[3];
    const int* ei11  = (const int*)d_in[4];
    const int* ei10  = (const int*)d_in[5];
    const int* ei21  = (const int*)d_in[6];
    const float* W0  = (const float*)d_in[7];  const float* b0 = (const float*)d_in[8];
    const float* W1  = (const float*)d_in[9];  const float* b1 = (const float*)d_in[10];
    const float* W2  = (const float*)d_in[11]; const float* b2 = (const float*)d_in[12];
    const float* as00 = (const float*)d_in[13]; const float* ad00 = (const float*)d_in[14];
    const float* as11 = (const float*)d_in[15]; const float* ad11 = (const float*)d_in[16];
    const float* as10 = (const float*)d_in[17]; const float* ad10 = (const float*)d_in[18];
    const float* as21 = (const float*)d_in[19]; const float* ad21 = (const float*)d_in[20];
    const float* kw  = (const float*)d_in[21]; const float* kb  = (const float*)d_in[22];
    const float* q   = (const float*)d_in[23];
    const float* lw  = (const float*)d_in[24]; const float* lb  = (const float*)d_in[25];
    float* out = (float*)d_out;

    char* p = (char*)d_ws;
    auto alloc = [&](size_t bytes) {
        char* r = p;
        p += (bytes + 255) & ~(size_t)255;
        return r;
    };
    unsigned char* h0 = (unsigned char*)alloc((size_t)N0 * 128);   // fp8 [N][128]
    unsigned char* h1 = (unsigned char*)alloc((size_t)N1 * 128);
    unsigned char* h2 = (unsigned char*)alloc((size_t)N2 * 128);
    _Float16* o_as00 = (_Float16*)alloc((size_t)N0 * 16);
    _Float16* o_ad00 = (_Float16*)alloc((size_t)N0 * 16);
    _Float16* o_as11 = (_Float16*)alloc((size_t)N1 * 16);
    _Float16* o_ad11 = (_Float16*)alloc((size_t)N1 * 16);
    _Float16* o_as10 = (_Float16*)alloc((size_t)N1 * 16);   // src of b10 = cell1
    _Float16* o_ad10 = (_Float16*)alloc((size_t)N0 * 16);   // dst of b10 = cell0
    _Float16* o_as21 = (_Float16*)alloc((size_t)N2 * 16);   // src of b21 = cell2
    _Float16* o_ad21 = (_Float16*)alloc((size_t)N1 * 16);   // dst of b21 = cell1
    int* off    = (int*)alloc((size_t)ND * 4);
    int* cursor = (int*)alloc((size_t)ND * 4);
    int* part   = (int*)alloc((size_t)512 * 4);
    int* srcs   = (int*)alloc((size_t)EE * 4);
    unsigned char* agg = (unsigned char*)alloc((size_t)ND * 128);  // fp8 [u00|b10|u11|b21]
    _Float16* wtg0 = (_Float16*)alloc(128 * 64 * 2);
    _Float16* wtg1 = (_Float16*)alloc(128 * 64 * 2);
    _Float16* wtg2 = (_Float16*)alloc(128 * 64 * 2);
    _Float16* adtg0 = (_Float16*)alloc(32 * 64 * 2);
    _Float16* adtg1 = (_Float16*)alloc(32 * 64 * 2);
    _Float16* adtg2 = (_Float16*)alloc(32 * 64 * 2);
    float* bdcg = (float*)alloc(3 * 32 * 4);
    unsigned char* kwf8 = (unsigned char*)alloc(144 * 128);
    // ---- zero region (contiguous) ----
    char* zstart = p;
    int* cnt = (int*)alloc((size_t)ND * 4);
    float* colsum2 = (float*)alloc(8 * 4);
    float* score   = (float*)alloc(4 * 4);
    unsigned int* done = (unsigned int*)alloc(4);
    size_t zbytes = (size_t)(p - zstart);

    (void)hipMemsetAsync(zstart, 0, zbytes, stream);

    // A: prep v2 (weights only, 32 blocks)
    PrepT pp0 = {W0, b0, as00, ad00, ad10, nullptr, wtg0, adtg0, bdcg + 0};
    PrepT pp1 = {W1, b1, as11, ad11, as10, ad21,    wtg1, adtg1, bdcg + 32};
    PrepT pp2 = {W2, b2, as21, nullptr, nullptr, nullptr, wtg2, adtg2, bdcg + 64};
    prep_kernel<<<32, 256, 0, stream>>>(pp0, pp1, pp2, kw, lw, kwf8);

    // B: proj v8 (QUARTER repack tile -> ~24.9 KB LDS, 6 blocks/CU)
    PT t0 = {x0, b0, h0,
             o_as00, o_ad00, o_ad10, nullptr,
             wtg0, adtg0, bdcg + 0,
             N0, 3125, 0, 296};
    PT t1 = {x1, b1, h1,
             o_as11, o_ad11, o_as10, o_ad21,
             wtg1, adtg1, bdcg + 32,
             N1, 6250, 296, 584};
    PT t2 = {x2, b2, h2,
             o_as21, nullptr, nullptr, nullptr,
             wtg2, adtg2, bdcg + 64,
             N2, 1563, 880, 144};
    proj_mfma<<<PROJ_BLKS + CNT_BLKS, 256, 0, stream>>>(t0, t1, t2,
        ei00, ei10, ei11, ei21, cnt);

    // C1: scan1 (chunk totals; needs final cnt from proj's count blocks)
    scan1_kernel<<<NB, 256, 0, stream>>>(cnt, part);

    // C2: scan2+scan3 fused
    scan23_kernel<<<NB, 256, 0, stream>>>(cnt, part, off, cursor);

    // D: fill v2 (CSR placement only)
    fill_kernel<<<(EE + 255) / 256, 256, 0, stream>>>(ei00, ei10, ei11, ei21,
                                                      cursor, srcs);

    // E: gather v5.2 (srcs prefetch-ahead)
    gather_kernel<<<ND / 32, 256, 0, stream>>>(cnt, off, srcs, h0, h1, h2,
        o_as00, o_ad00, o_as10, o_ad10, o_as11, o_ad11, o_as21, o_ad21, agg);

    // F: semantic v7 (full-depth prefetch, (256,4), grid 1024)
    semantic_kernel<<<1024, 256, 0, stream>>>(agg, kwf8, kb, q, lb,
                                              colsum2, score, done, out);
}

// Round 18
// 246.801 us; speedup vs baseline: 1.0090x; 1.0090x over previous
//
#include <hip/hip_runtime.h>
#include <hip/hip_fp16.h>

#define N0 50000
#define N1 100000
#define N2 25000
#define E00 200000
#define E11 200000
#define E10 100000
#define E21 50000
#define EE  550000   // E00+E10+E11+E21 (concatenated edge space)
#define ND  300000   // 50000(u00)+50000(b10)+100000(u11)+100000(b21) dst slots
#define NB  293      // ceil(ND/1024) scan blocks
#define NT_ALL 18750 // ND/16 semantic tiles
#define HID 128
#define INC 64
#define CNT_BLKS 2149  // ceil(EE/256) edge-count blocks (in proj's launch)

typedef _Float16 half8 __attribute__((ext_vector_type(8)));
typedef _Float16 half4_t __attribute__((ext_vector_type(4)));
typedef float float4v __attribute__((ext_vector_type(4)));
typedef float floatx2 __attribute__((ext_vector_type(2)));

__device__ __forceinline__ void decode_edge(
    int e, const int* ei00, const int* ei10, const int* ei11, const int* ei21,
    int& src, int& slot)
{
    if (e < E00)                    { src = ei00[e];               slot = ei00[E00 + e]; }
    else if (e < E00 + E10)         { int i = e - E00;             src = ei10[i]; slot = 50000  + ei10[E10 + i]; }
    else if (e < E00 + E10 + E11)   { int i = e - E00 - E10;       src = ei11[i]; slot = 100000 + ei11[E11 + i]; }
    else                            { int i = e - E00 - E10 - E11; src = ei21[i]; slot = 200000 + ei21[E21 + i]; }
}

// ---------------------------------------------------------------------------
// Kernel A: prep v2 — WEIGHTS ONLY (32 blocks, ~3 us).
// ---------------------------------------------------------------------------
struct PrepT {
    const float* W; const float* bias;
    const float* av0; const float* av1; const float* av2; const float* av3;
    _Float16* wtg; _Float16* adtg; float* bdc;
};

__global__ __launch_bounds__(256) void prep_kernel(
    PrepT p0, PrepT p1, PrepT p2,
    const float* __restrict__ kw, const float* __restrict__ lw,
    unsigned char* __restrict__ kwf8)
{
    if (blockIdx.x >= 24) {
        int base = (blockIdx.x - 24) * 256 + threadIdx.x;
        for (int it = 0; it < 9; ++it) {
            int idx = base + it * 2048;
            int f = idx >> 7, g = idx & 127;
            float v;
            if (f < 128)      v = 2.0f * kw[g * 128 + f];   // pre-scale by 2 (exact)
            else if (f < 130) v = lw[g * 2 + (f - 128)];
            else              v = 0.f;
            int r = __builtin_amdgcn_cvt_pk_fp8_f32(v, 0.f, 0, false);
            kwf8[idx] = (unsigned char)r;
        }
        return;
    }
    PrepT P = (blockIdx.x >= 16) ? p2 : (blockIdx.x >= 8) ? p1 : p0;
    const int lb = blockIdx.x & 7;
    const int t2 = lb * 256 + threadIdx.x;   // 0..2047
    {
        int f = t2 >> 4, g0 = (t2 & 15) * 4;
        half4_t v;
#pragma unroll
        for (int j = 0; j < 4; ++j) v[j] = (_Float16)P.W[(g0 + j) * 128 + f];
        *(half4_t*)&P.wtg[f * 64 + g0] = v;
    }
    {
        int c = t2 >> 6, g = t2 & 63;
        const float* av = (c < 8) ? P.av0 : (c < 16) ? P.av1 : (c < 24) ? P.av2 : P.av3;
        float v = 0.f;
        if (av) {
            int hh = c & 7;
#pragma unroll
            for (int d = 0; d < 16; ++d)
                v += P.W[g * 128 + hh * 16 + d] * av[hh * 16 + d];
        }
        P.adtg[c * 64 + g] = (_Float16)v;
    }
    if (lb == 0 && threadIdx.x < 32) {
        int c = threadIdx.x;
        const float* av = (c < 8) ? P.av0 : (c < 16) ? P.av1 : (c < 24) ? P.av2 : P.av3;
        float v = 0.f;
        if (av) {
            int hh = c & 7;
#pragma unroll
            for (int d = 0; d < 16; ++d)
                v += P.bias[hh * 16 + d] * av[hh * 16 + d];
        }
        P.bdc[c] = v;
    }
}

// ---------------------------------------------------------------------------
// Kernel B: proj_mfma v7 (+edge-count fused) — R16-VERIFIED configuration
// (reverted from v8: quarter-tile's 2B ht accesses caused 6x bank conflicts,
// eating the occupancy gain — R17). v7: LDS-B + narrow accumulator + HALF
// repack tile; ht [4][16][68] = 8.7 KB, 4B fp8 packs per lane (conflict-OK);
// LDS total ~29.8 KB -> 5 blocks/CU. Bare launch bounds (natural regs).
// LDS->occupancy ladder closed: 38.9KB/4blk/44us -> 29.8KB/5blk/<40us ->
// 24.9KB/6blk/42us (bank-conflict regression). This is the optimum.
// ---------------------------------------------------------------------------
struct PT {
    const float* x; const float* bias; unsigned char* h;
    _Float16* ao0; _Float16* ao1; _Float16* ao2; _Float16* ao3;
    const _Float16* wtg; const _Float16* adtg; const float* bdc;
    int N; int ntiles; int bstart; int nblocks;
};

#define PROJ_BLKS 1024

__global__ __launch_bounds__(256) void proj_mfma(
    PT t0, PT t1, PT t2,
    const int* __restrict__ ei00, const int* __restrict__ ei10,
    const int* __restrict__ ei11, const int* __restrict__ ei21,
    int* __restrict__ cnt)
{
    __shared__ _Float16 ht[4][16][68];     // 8.7 KB: per-wave HALF h tile (f16)
    __shared__ half8 lbs[1280];            // 20 KB: [nt*2+kb][lane] | bd at 1024+
    __shared__ float biasl[128];
    __shared__ float bdcl[32];
    const int tid = threadIdx.x;
    const int lane = tid & 63, wv = tid >> 6;
    const int fi = lane & 15, hi = lane >> 4;

    if (blockIdx.x >= PROJ_BLKS) {
        // edge count: decode + atomic
        int e = (blockIdx.x - PROJ_BLKS) * 256 + tid;
        if (e >= EE) return;
        int src, slot;
        decode_edge(e, ei00, ei10, ei11, ei21, src, slot);
        atomicAdd(&cnt[slot], 1);
        return;
    }

    PT A = (blockIdx.x >= t2.bstart) ? t2 : (blockIdx.x >= t1.bstart) ? t1 : t0;

    const int stride = A.nblocks * 4;
    const int tb = (blockIdx.x - A.bstart) * 4 + wv;

    // ---- issue ALL 3 tiles' x loads up front (in flight across staging) ----
    float4 xa0, xa1, xa2, xa3, xb0, xb1, xb2, xb3, xc0, xc1, xc2, xc3;
#define LOADX(I, U0, U1, U2, U3)                                                \
    {   const int tt = tb + (I) * stride;                                       \
        if (tt < A.ntiles) {                                                    \
            int rsrc = tt * 16 + fi; if (rsrc >= A.N) rsrc = A.N - 1;           \
            const float* xp = A.x + (size_t)rsrc * 64 + hi * 8;                 \
            U0 = *(const float4*)(xp);      U1 = *(const float4*)(xp + 4);      \
            U2 = *(const float4*)(xp + 32); U3 = *(const float4*)(xp + 36);     \
        } }
    LOADX(0, xa0, xa1, xa2, xa3)
    LOADX(1, xb0, xb1, xb2, xb3)
    LOADX(2, xc0, xc1, xc2, xc3)

    // ---- stage B into LDS: entries 0..1023 = bfr[nt][kb], 1024..1279 = bd ----
#pragma unroll
    for (int it = 0; it < 5; ++it) {
        int e = it * 256 + tid;            // 0..1279
        int ln = e & 63;
        int efi = ln & 15, ehi = ln >> 4;
        if (e < 1024) {
            int nt = e >> 7, kb = (e >> 6) & 1;
            lbs[e] = *(const half8*)&A.wtg[(nt * 16 + efi) * 64 + kb * 32 + ehi * 8];
        } else {
            int e2 = e - 1024;
            int t = e2 >> 7, kb = (e2 >> 6) & 1;
            lbs[e] = *(const half8*)&A.adtg[(t * 16 + efi) * 64 + kb * 32 + ehi * 8];
        }
    }
    if (tid < 128)      biasl[tid] = A.bias[tid];
    else if (tid < 160) bdcl[tid - 128] = A.bdc[tid - 128];
    __syncthreads();

    const float bdc0 = bdcl[fi];
    const float bdc1 = bdcl[16 + fi];
    _Float16* aolo = (fi >= 8) ? A.ao1 : A.ao0;
    _Float16* aohi = (fi >= 8) ? A.ao3 : A.ao2;
    const bool has_hi = (A.ao2 != nullptr) || (A.ao3 != nullptr);

#define COMPX(I, U0, U1, U2, U3)                                                \
    {   const int tt = tb + (I) * stride;                                       \
        if (tt < A.ntiles) {                                                    \
            const int base = tt * 16;                                           \
            half8 a0, a1;                                                       \
            a0[0] = (_Float16)U0.x; a0[1] = (_Float16)U0.y;                     \
            a0[2] = (_Float16)U0.z; a0[3] = (_Float16)U0.w;                     \
            a0[4] = (_Float16)U1.x; a0[5] = (_Float16)U1.y;                     \
            a0[6] = (_Float16)U1.z; a0[7] = (_Float16)U1.w;                     \
            a1[0] = (_Float16)U2.x; a1[1] = (_Float16)U2.y;                     \
            a1[2] = (_Float16)U2.z; a1[3] = (_Float16)U2.w;                     \
            a1[4] = (_Float16)U3.x; a1[5] = (_Float16)U3.y;                     \
            a1[6] = (_Float16)U3.z; a1[7] = (_Float16)U3.w;                     \
            _Pragma("unroll 2")                                                 \
            for (int hf = 0; hf < 2; ++hf) {                                    \
                _Pragma("unroll 2")                                             \
                for (int n4 = 0; n4 < 4; ++n4) {                                \
                    int nt = hf * 4 + n4;                                       \
                    half8 b0 = lbs[(nt * 2 + 0) * 64 + lane];                   \
                    half8 b1 = lbs[(nt * 2 + 1) * 64 + lane];                   \
                    float4v z = {0.f, 0.f, 0.f, 0.f};                           \
                    z = __builtin_amdgcn_mfma_f32_16x16x32_f16(a0, b0, z, 0, 0, 0); \
                    z = __builtin_amdgcn_mfma_f32_16x16x32_f16(a1, b1, z, 0, 0, 0); \
                    float bv = biasl[nt * 16 + fi];                             \
                    _Pragma("unroll")                                           \
                    for (int r = 0; r < 4; ++r)                                 \
                        ht[wv][hi * 4 + r][n4 * 16 + fi] = (_Float16)(z[r] + bv); \
                }                                                               \
                _Pragma("unroll")                                               \
                for (int i = 0; i < 4; ++i) {                                   \
                    int row = i * 4 + hi;                                       \
                    int node = base + row;                                      \
                    if (node < A.N) {                                           \
                        float v0 = (float)ht[wv][row][fi * 4 + 0];              \
                        float v1 = (float)ht[wv][row][fi * 4 + 1];              \
                        float v2 = (float)ht[wv][row][fi * 4 + 2];              \
                        float v3 = (float)ht[wv][row][fi * 4 + 3];              \
                        int pa = __builtin_amdgcn_cvt_pk_fp8_f32(v0, v1, 0, false); \
                        pa = __builtin_amdgcn_cvt_pk_fp8_f32(v2, v3, pa, true); \
                        *(int*)(A.h + (size_t)node * 128 + hf * 64 + fi * 4) = pa; \
                    }                                                           \
                }                                                               \
            }                                                                   \
            float4v d0 = {0.f, 0.f, 0.f, 0.f};                                  \
            d0 = __builtin_amdgcn_mfma_f32_16x16x32_f16(a0, lbs[1024 + lane], d0, 0, 0, 0); \
            d0 = __builtin_amdgcn_mfma_f32_16x16x32_f16(a1, lbs[1088 + lane], d0, 0, 0, 0); \
            float4v d1 = {0.f, 0.f, 0.f, 0.f};                                  \
            if (has_hi) {                                                       \
                d1 = __builtin_amdgcn_mfma_f32_16x16x32_f16(a0, lbs[1152 + lane], d1, 0, 0, 0); \
                d1 = __builtin_amdgcn_mfma_f32_16x16x32_f16(a1, lbs[1216 + lane], d1, 0, 0, 0); \
            }                                                                   \
            if (aolo) {                                                         \
                _Pragma("unroll")                                               \
                for (int r = 0; r < 4; ++r) {                                   \
                    int node = base + hi * 4 + r;                               \
                    if (node < A.N) aolo[(size_t)node * 8 + (fi & 7)] = (_Float16)(d0[r] + bdc0); \
                }                                                               \
            }                                                                   \
            if (aohi) {                                                         \
                _Pragma("unroll")                                               \
                for (int r = 0; r < 4; ++r) {                                   \
                    int node = base + hi * 4 + r;                               \
                    if (node < A.N) aohi[(size_t)node * 8 + (fi & 7)] = (_Float16)(d1[r] + bdc1); \
                }                                                               \
            }                                                                   \
        } }
    COMPX(0, xa0, xa1, xa2, xa3)
    COMPX(1, xb0, xb1, xb2, xb3)
    COMPX(2, xc0, xc1, xc2, xc3)
}

// ---------------------------------------------------------------------------
// Kernel C1: scan1 — per-1024-chunk totals of cnt.
// ---------------------------------------------------------------------------
__global__ __launch_bounds__(256) void scan1_kernel(
    const int* __restrict__ cnt, int* __restrict__ part)
{
    __shared__ int swt[4];
    const int tid = threadIdx.x;
    const int b = blockIdx.x;
    int i0 = b * 1024 + tid * 4;
    int s = 0;
#pragma unroll
    for (int k = 0; k < 4; ++k) { int i = i0 + k; s += (i < ND) ? cnt[i] : 0; }
#pragma unroll
    for (int off = 1; off < 64; off <<= 1) s += __shfl_xor(s, off);
    if ((tid & 63) == 0) swt[tid >> 6] = s;
    __syncthreads();
    if (tid == 0) part[b] = swt[0] + swt[1] + swt[2] + swt[3];
}

// ---------------------------------------------------------------------------
// Kernel C2: scan23 — each block replicates the 293-partial exclusive scan
// locally, then does scan3's offset/cursor writes.
// ---------------------------------------------------------------------------
__global__ __launch_bounds__(256) void scan23_kernel(
    const int* __restrict__ cnt, const int* __restrict__ part,
    int* __restrict__ off, int* __restrict__ cursor)
{
    __shared__ int sd[256];
    __shared__ int pex[512];
    __shared__ int wt[4];
    const int tid = threadIdx.x, b = blockIdx.x;
    const int lane = tid & 63, wv = tid >> 6;

    int p0 = (2 * tid     < NB) ? part[2 * tid]     : 0;
    int p1 = (2 * tid + 1 < NB) ? part[2 * tid + 1] : 0;
    int ps = p0 + p1;
    sd[tid] = ps; __syncthreads();
    for (int d = 1; d < 256; d <<= 1) {
        int v = (tid >= d) ? sd[tid - d] : 0;
        __syncthreads();
        sd[tid] += v;
        __syncthreads();
    }
    int exc = sd[tid] - ps;
    pex[2 * tid] = exc;
    pex[2 * tid + 1] = exc + p0;
    __syncthreads();

    int i0 = b * 1024 + tid * 4;
    int v[4];
#pragma unroll
    for (int k = 0; k < 4; ++k) { int i = i0 + k; v[k] = (i < ND) ? cnt[i] : 0; }
    int ts = v[0] + v[1] + v[2] + v[3];
    int inc = ts;
#pragma unroll
    for (int d = 1; d < 64; d <<= 1) {
        int u = __shfl_up(inc, d);
        if (lane >= d) inc += u;
    }
    int wexc = inc - ts;
    if (lane == 63) wt[wv] = inc;
    __syncthreads();
    int wbase = 0;
    for (int w = 0; w < wv; ++w) wbase += wt[w];
    int base = pex[b] + wbase + wexc;
    int pre = 0;
#pragma unroll
    for (int k = 0; k < 4; ++k) {
        int i = i0 + k;
        if (i < ND) { off[i] = base + pre; cursor[i] = base + pre; }
        pre += v[k];
    }
}

// ---------------------------------------------------------------------------
// Fill v2: CSR placement ONLY (decode edge, cursor atomic, 4B srcs scatter).
// ---------------------------------------------------------------------------
__global__ __launch_bounds__(256) void fill_kernel(
    const int* __restrict__ ei00, const int* __restrict__ ei10,
    const int* __restrict__ ei11, const int* __restrict__ ei21,
    int* __restrict__ cursor, int* __restrict__ srcs)
{
    int e = blockIdx.x * 256 + threadIdx.x;
    if (e >= EE) return;
    int src, slot;
    decode_edge(e, ei00, ei10, ei11, ei21, src, slot);
    int pos = atomicAdd(&cursor[slot], 1);
    srcs[pos] = src;
}

// ---------------------------------------------------------------------------
// Gather v5.2: 8 slots/wave, in-loop f16 attention weights, srcs index
// prefetch one pair ahead (removes the L2 hop from the per-iteration chain).
// ---------------------------------------------------------------------------
__global__ __launch_bounds__(256) void gather_kernel(
    const int* __restrict__ cnt, const int* __restrict__ off,
    const int* __restrict__ srcs,
    const unsigned char* __restrict__ h0, const unsigned char* __restrict__ h1,
    const unsigned char* __restrict__ h2,
    const _Float16* __restrict__ as00, const _Float16* __restrict__ ad00,
    const _Float16* __restrict__ as10, const _Float16* __restrict__ ad10,
    const _Float16* __restrict__ as11, const _Float16* __restrict__ ad11,
    const _Float16* __restrict__ as21, const _Float16* __restrict__ ad21,
    unsigned char* __restrict__ agg)
{
    const int gid = blockIdx.x * 256 + threadIdx.x;
    const int lane = gid & 63;
    const int g8 = lane >> 3, sub = lane & 7;
    const int slot = (gid >> 6) * 8 + g8;           // grid sized so slot < ND
    const unsigned char* hs;
    const _Float16* asp;
    float adv;
    if (slot < 50000)       { hs = h0; asp = as00; adv = (float)ad00[(size_t)slot * 8 + sub]; }
    else if (slot < 100000) { hs = h1; asp = as10; adv = (float)ad10[(size_t)(slot - 50000) * 8 + sub]; }
    else if (slot < 200000) { hs = h1; asp = as11; adv = (float)ad11[(size_t)(slot - 100000) * 8 + sub]; }
    else                    { hs = h2; asp = as21; adv = (float)ad21[(size_t)(slot - 200000) * 8 + sub]; }
    const int deg = cnt[slot], st = off[slot];

    int degm = deg;
    degm = max(degm, __shfl_xor(degm, 8));
    degm = max(degm, __shfl_xor(degm, 16));
    degm = max(degm, __shfl_xor(degm, 32));

    float acc[16];
#pragma unroll
    for (int j = 0; j < 16; ++j) acc[j] = 0.f;
    float sw = 0.f;

    // prefetch first pair's indices
    bool a0n = (0 < deg), a1n = (1 < deg);
    int s0n = 0, s1n = 0;
    if (a0n) s0n = srcs[st + 0];
    if (a1n) s1n = srcs[st + 1];

    int i = 0;
    for (; i + 2 <= degm; i += 2) {
        const bool a0 = a0n, a1 = a1n;
        const int s0 = s0n, s1 = s1n;
        // prefetch next pair's indices (off the critical chain)
        a0n = (i + 2 < deg); a1n = (i + 3 < deg);
        if (a0n) s0n = srcs[st + i + 2];
        if (a1n) s1n = srcs[st + i + 3];

        float w0 = 0.f, w1 = 0.f;
        int4 v0 = {0, 0, 0, 0}, v1 = {0, 0, 0, 0};
        if (a0) { float v = (float)asp[(size_t)s0 * 8 + sub] + adv;
                  v = v > 0.f ? v : 0.2f * v;
                  w0 = __expf(v);
                  v0 = *(const int4*)(hs + (size_t)s0 * 128 + sub * 16); }
        if (a1) { float v = (float)asp[(size_t)s1 * 8 + sub] + adv;
                  v = v > 0.f ? v : 0.2f * v;
                  w1 = __expf(v);
                  v1 = *(const int4*)(hs + (size_t)s1 * 128 + sub * 16); }
        const int wa[4] = {v0.x, v0.y, v0.z, v0.w};
        const int wb[4] = {v1.x, v1.y, v1.z, v1.w};
#pragma unroll
        for (int k = 0; k < 4; ++k) {
            floatx2 fa0 = __builtin_amdgcn_cvt_pk_f32_fp8(wa[k], false);
            floatx2 fa1 = __builtin_amdgcn_cvt_pk_f32_fp8(wa[k], true);
            floatx2 fb0 = __builtin_amdgcn_cvt_pk_f32_fp8(wb[k], false);
            floatx2 fb1 = __builtin_amdgcn_cvt_pk_f32_fp8(wb[k], true);
            acc[4 * k + 0] += w0 * fa0.x + w1 * fb0.x;
            acc[4 * k + 1] += w0 * fa0.y + w1 * fb0.y;
            acc[4 * k + 2] += w0 * fa1.x + w1 * fb1.x;
            acc[4 * k + 3] += w0 * fa1.y + w1 * fb1.y;
        }
        sw += w0 + w1;
    }
    if (i < degm) {
        // tail: a0n/s0n already hold index i's guard/value
        float w0 = 0.f;
        int4 v0 = {0, 0, 0, 0};
        if (a0n) { float v = (float)asp[(size_t)s0n * 8 + sub] + adv;
                   v = v > 0.f ? v : 0.2f * v;
                   w0 = __expf(v);
                   v0 = *(const int4*)(hs + (size_t)s0n * 128 + sub * 16); }
        const int wa[4] = {v0.x, v0.y, v0.z, v0.w};
#pragma unroll
        for (int k = 0; k < 4; ++k) {
            floatx2 fa0 = __builtin_amdgcn_cvt_pk_f32_fp8(wa[k], false);
            floatx2 fa1 = __builtin_amdgcn_cvt_pk_f32_fp8(wa[k], true);
            acc[4 * k + 0] += w0 * fa0.x;
            acc[4 * k + 1] += w0 * fa0.y;
            acc[4 * k + 2] += w0 * fa1.x;
            acc[4 * k + 3] += w0 * fa1.y;
        }
        sw += w0;
    }

    float rr = __builtin_amdgcn_rcpf(sw + 1e-16f);
    int4 o;
    int pk[4];
#pragma unroll
    for (int k = 0; k < 4; ++k) {
        float r0 = fmaxf(acc[4 * k + 0] * rr, 0.f);
        float r1 = fmaxf(acc[4 * k + 1] * rr, 0.f);
        float r2 = fmaxf(acc[4 * k + 2] * rr, 0.f);
        float r3 = fmaxf(acc[4 * k + 3] * rr, 0.f);
        int p = __builtin_amdgcn_cvt_pk_fp8_f32(r0, r1, 0, false);
        p = __builtin_amdgcn_cvt_pk_fp8_f32(r2, r3, p, true);
        pk[k] = p;
    }
    o.x = pk[0]; o.y = pk[1]; o.z = pk[2]; o.w = pk[3];
    *(int4*)(agg + (size_t)slot * 128 + sub * 16) = o;
}

// ---------------------------------------------------------------------------
// Semantic v7 (verified R9-R17): v6 structure + full-depth load prefetch.
// (256,4), grid 1024 — verified allocator point; knob closed.
// ---------------------------------------------------------------------------
__global__ __launch_bounds__(256, 4) void semantic_kernel(
    const unsigned char* __restrict__ agg, const unsigned char* __restrict__ kwf8,
    const float* __restrict__ kb, const float* __restrict__ q,
    const float* __restrict__ lb,
    float* __restrict__ cs2, float* __restrict__ score,
    unsigned int* __restrict__ done, float* __restrict__ out)
{
    __shared__ long lbs[2304];     // 18 KB B frags: [g(9)][kk(4)][lane(64)] x 8B
    __shared__ float kbl[128];     // 2*k_b
    __shared__ float qla[128];     // 2*q
    __shared__ float redv[12];
    const int tid = threadIdx.x;
    const int lane = tid & 63, wv = tid >> 6;
    const int fi = lane & 15, hi = lane >> 4;

    if (tid < 12) redv[tid] = 0.f;
    for (int it = 0; it < 9; ++it) {
        int e = it * 256 + tid;            // 0..2303
        int gk = e >> 6, lp = e & 63;
        int gw = gk >> 2, kkw = gk & 3;
        int fiw = lp & 15, hiw = lp >> 4;
        lbs[e] = *(const long*)&kwf8[(gw * 16 + fiw) * 128 + kkw * 32 + hiw * 8];
    }
    if (tid < 128) kbl[tid] = 2.f * kb[tid];
    else           qla[tid - 128] = 2.f * q[tid - 128];

    const int wid = blockIdx.x * 4 + wv;
    const int nw = gridDim.x * 4;          // 4096

    long af0[4], af1[4], af2[4], af3[4], af4[4];
#define LOADT(I, AF)                                                            \
    {   const int tt = wid + (I) * nw;                                          \
        if (tt < NT_ALL) {                                                      \
            const unsigned char* rowp = agg + ((size_t)(tt * 16 + fi) * 128 + hi * 8); \
            AF[0] = *(const long*)(rowp);       AF[1] = *(const long*)(rowp + 32); \
            AF[2] = *(const long*)(rowp + 64);  AF[3] = *(const long*)(rowp + 96); \
        } else { AF[0] = 0; AF[1] = 0; AF[2] = 0; AF[3] = 0; } }
    LOADT(0, af0) LOADT(1, af1) LOADT(2, af2) LOADT(3, af3) LOADT(4, af4)

    __syncthreads();   // staging visible; global loads remain in flight

    float c4q = 0.f;
#pragma unroll
    for (int g = 0; g < 8; ++g) c4q += 2.f * qla[g * 16 + fi];

    const long* lbl = lbs + lane;

    float sc[4] = {0.f, 0.f, 0.f, 0.f};
    float cs[4] = {0.f, 0.f, 0.f, 0.f};

#define COMPT(I, AF)                                                            \
    {   const int tt = wid + (I) * nw;                                          \
        if (tt < NT_ALL) {                                                      \
            const int m = (tt >= 12500) ? 3 : (tt >= 6250) ? 2 : (tt >= 3125) ? 1 : 0; \
            float tn0 = 0.f, tn1 = 0.f, tn2 = 0.f, tn3 = 0.f, tcs = 0.f;        \
            _Pragma("unroll 3")                                                 \
            for (int g = 0; g < 9; ++g) {                                       \
                long b0 = lbl[g * 256 + 0];                                     \
                long b1 = lbl[g * 256 + 64];                                    \
                long b2 = lbl[g * 256 + 128];                                   \
                long b3 = lbl[g * 256 + 192];                                   \
                if (g < 8) {                                                    \
                    float kbg = kbl[g * 16 + fi];                               \
                    float qg  = qla[g * 16 + fi];                               \
                    float4v c = {kbg, kbg, kbg, kbg};                           \
                    c = __builtin_amdgcn_mfma_f32_16x16x32_fp8_fp8(AF[0], b0, c, 0, 0, 0); \
                    c = __builtin_amdgcn_mfma_f32_16x16x32_fp8_fp8(AF[1], b1, c, 0, 0, 0); \
                    c = __builtin_amdgcn_mfma_f32_16x16x32_fp8_fp8(AF[2], b2, c, 0, 0, 0); \
                    c = __builtin_amdgcn_mfma_f32_16x16x32_fp8_fp8(AF[3], b3, c, 0, 0, 0); \
                    float e0 = __expf(c[0]); tn0 += qg * __builtin_amdgcn_rcpf(e0 + 1.f); \
                    float e1 = __expf(c[1]); tn1 += qg * __builtin_amdgcn_rcpf(e1 + 1.f); \
                    float e2 = __expf(c[2]); tn2 += qg * __builtin_amdgcn_rcpf(e2 + 1.f); \
                    float e3 = __expf(c[3]); tn3 += qg * __builtin_amdgcn_rcpf(e3 + 1.f); \
                } else {                                                        \
                    float4v c = {0.f, 0.f, 0.f, 0.f};                           \
                    c = __builtin_amdgcn_mfma_f32_16x16x32_fp8_fp8(AF[0], b0, c, 0, 0, 0); \
                    c = __builtin_amdgcn_mfma_f32_16x16x32_fp8_fp8(AF[1], b1, c, 0, 0, 0); \
                    c = __builtin_amdgcn_mfma_f32_16x16x32_fp8_fp8(AF[2], b2, c, 0, 0, 0); \
                    c = __builtin_amdgcn_mfma_f32_16x16x32_fp8_fp8(AF[3], b3, c, 0, 0, 0); \
                    tcs = c[0] + c[1] + c[2] + c[3];                            \
                }                                                               \
            }                                                                   \
            float tsc = c4q - ((tn0 + tn1) + (tn2 + tn3));                      \
            if (m == 0)      { sc[0] += tsc; cs[0] += tcs; }                    \
            else if (m == 1) { sc[1] += tsc; cs[1] += tcs; }                    \
            else if (m == 2) { sc[2] += tsc; cs[2] += tcs; }                    \
            else             { sc[3] += tsc; cs[3] += tcs; }                    \
        } }
    COMPT(0, af0) COMPT(1, af1) COMPT(2, af2) COMPT(3, af3) COMPT(4, af4)

#pragma unroll
    for (int m = 0; m < 4; ++m) {
        float s = sc[m];
#pragma unroll
        for (int off = 1; off < 64; off <<= 1) s += __shfl_xor(s, off);
        if (lane == 0 && s != 0.f) atomicAdd(&redv[m], s);
        float v = cs[m];
        v += __shfl_xor(v, 16);
        v += __shfl_xor(v, 32);
        if (hi == 0 && fi < 2 && v != 0.f) atomicAdd(&redv[4 + 2 * m + fi], v);
    }
    __syncthreads();
    if (tid < 4)              atomicAdd(&score[tid], redv[tid]);
    if (tid >= 4 && tid < 12) atomicAdd(&cs2[tid - 4], redv[tid]);

    // last-block final epilogue
    __syncthreads();
    if (tid == 0) {
        __threadfence();
        unsigned int old = atomicAdd(done, 1u);
        if (old == gridDim.x - 1) {
            __threadfence();
            float s0 = score[0] / (float)N0;
            float s1 = score[1] / (float)N0;
            float s2 = score[2] / (float)N1;
            float s3 = score[3] / (float)N1;
            float m0 = fmaxf(s0, s1);
            float e0 = __expf(s0 - m0), e1 = __expf(s1 - m0);
            float a0 = e0 / (e0 + e1), a1 = e1 / (e0 + e1);
            float m1 = fmaxf(s2, s3);
            float e2 = __expf(s2 - m1), e3 = __expf(s3 - m1);
            float a2 = e2 / (e2 + e3), a3 = e3 / (e2 + e3);
            float z0 = a0 * cs2[0] + a1 * cs2[2] + a2 * cs2[4] + a3 * cs2[6] + lb[0];
            float z1 = a0 * cs2[1] + a1 * cs2[3] + a2 * cs2[5] + a3 * cs2[7] + lb[1];
            out[0] = 1.f / (1.f + __expf(-z0));
            out[1] = 1.f / (1.f + __expf(-z1));
        }
    }
}

extern "C" void kernel_launch(void* const* d_in, const int* in_sizes, int n_in,
                              void* d_out, int out_size, void* d_ws, size_t ws_size,
                              hipStream_t stream)
{
    const float* x0  = (const float*)d_in[0];
    const float* x1  = (const float*)d_in[1];
    const float* x2  = (const float*)d_in[2];
    const int* ei00  = (const int*)d_in[3];
    const int* ei11  = (const int*)d_in[4];
    const int* ei10  = (const int*)d_in[5];
    const int* ei21  = (const int*)d_in[6];
    const float* W0  = (const float*)d_in[7];  const float* b0 = (const float*)d_in[8];
    const float* W1  = (const float*)d_in[9];  const float* b1 = (const float*)d_in[10];
    const float* W2  = (const float*)d_in[11]; const float* b2 = (const float*)d_in[12];
    const float* as00 = (const float*)d_in[13]; const float* ad00 = (const float*)d_in[14];
    const float* as11 = (const float*)d_in[15]; const float* ad11 = (const float*)d_in[16];
    const float* as10 = (const float*)d_in[17]; const float* ad10 = (const float*)d_in[18];
    const float* as21 = (const float*)d_in[19]; const float* ad21 = (const float*)d_in[20];
    const float* kw  = (const float*)d_in[21]; const float* kb  = (const float*)d_in[22];
    const float* q   = (const float*)d_in[23];
    const float* lw  = (const float*)d_in[24]; const float* lb  = (const float*)d_in[25];
    float* out = (float*)d_out;

    char* p = (char*)d_ws;
    auto alloc = [&](size_t bytes) {
        char* r = p;
        p += (bytes + 255) & ~(size_t)255;
        return r;
    };
    unsigned char* h0 = (unsigned char*)alloc((size_t)N0 * 128);   // fp8 [N][128]
    unsigned char* h1 = (unsigned char*)alloc((size_t)N1 * 128);
    unsigned char* h2 = (unsigned char*)alloc((size_t)N2 * 128);
    _Float16* o_as00 = (_Float16*)alloc((size_t)N0 * 16);
    _Float16* o_ad00 = (_Float16*)alloc((size_t)N0 * 16);
    _Float16* o_as11 = (_Float16*)alloc((size_t)N1 * 16);
    _Float16* o_ad11 = (_Float16*)alloc((size_t)N1 * 16);
    _Float16* o_as10 = (_Float16*)alloc((size_t)N1 * 16);   // src of b10 = cell1
    _Float16* o_ad10 = (_Float16*)alloc((size_t)N0 * 16);   // dst of b10 = cell0
    _Float16* o_as21 = (_Float16*)alloc((size_t)N2 * 16);   // src of b21 = cell2
    _Float16* o_ad21 = (_Float16*)alloc((size_t)N1 * 16);   // dst of b21 = cell1
    int* off    = (int*)alloc((size_t)ND * 4);
    int* cursor = (int*)alloc((size_t)ND * 4);
    int* part   = (int*)alloc((size_t)512 * 4);
    int* srcs   = (int*)alloc((size_t)EE * 4);
    unsigned char* agg = (unsigned char*)alloc((size_t)ND * 128);  // fp8 [u00|b10|u11|b21]
    _Float16* wtg0 = (_Float16*)alloc(128 * 64 * 2);
    _Float16* wtg1 = (_Float16*)alloc(128 * 64 * 2);
    _Float16* wtg2 = (_Float16*)alloc(128 * 64 * 2);
    _Float16* adtg0 = (_Float16*)alloc(32 * 64 * 2);
    _Float16* adtg1 = (_Float16*)alloc(32 * 64 * 2);
    _Float16* adtg2 = (_Float16*)alloc(32 * 64 * 2);
    float* bdcg = (float*)alloc(3 * 32 * 4);
    unsigned char* kwf8 = (unsigned char*)alloc(144 * 128);
    // ---- zero region (contiguous) ----
    char* zstart = p;
    int* cnt = (int*)alloc((size_t)ND * 4);
    float* colsum2 = (float*)alloc(8 * 4);
    float* score   = (float*)alloc(4 * 4);
    unsigned int* done = (unsigned int*)alloc(4);
    size_t zbytes = (size_t)(p - zstart);

    (void)hipMemsetAsync(zstart, 0, zbytes, stream);

    // A: prep v2 (weights only, 32 blocks)
    PrepT pp0 = {W0, b0, as00, ad00, ad10, nullptr, wtg0, adtg0, bdcg + 0};
    PrepT pp1 = {W1, b1, as11, ad11, as10, ad21,    wtg1, adtg1, bdcg + 32};
    PrepT pp2 = {W2, b2, as21, nullptr, nullptr, nullptr, wtg2, adtg2, bdcg + 64};
    prep_kernel<<<32, 256, 0, stream>>>(pp0, pp1, pp2, kw, lw, kwf8);

    // B: proj v7 (R16-verified: LDS-B + HALF repack tile, ~29.8 KB, 5 blk/CU)
    PT t0 = {x0, b0, h0,
             o_as00, o_ad00, o_ad10, nullptr,
             wtg0, adtg0, bdcg + 0,
             N0, 3125, 0, 296};
    PT t1 = {x1, b1, h1,
             o_as11, o_ad11, o_as10, o_ad21,
             wtg1, adtg1, bdcg + 32,
             N1, 6250, 296, 584};
    PT t2 = {x2, b2, h2,
             o_as21, nullptr, nullptr, nullptr,
             wtg2, adtg2, bdcg + 64,
             N2, 1563, 880, 144};
    proj_mfma<<<PROJ_BLKS + CNT_BLKS, 256, 0, stream>>>(t0, t1, t2,
        ei00, ei10, ei11, ei21, cnt);

    // C1: scan1 (chunk totals; needs final cnt from proj's count blocks)
    scan1_kernel<<<NB, 256, 0, stream>>>(cnt, part);

    // C2: scan2+scan3 fused
    scan23_kernel<<<NB, 256, 0, stream>>>(cnt, part, off, cursor);

    // D: fill v2 (CSR placement only)
    fill_kernel<<<(EE + 255) / 256, 256, 0, stream>>>(ei00, ei10, ei11, ei21,
                                                      cursor, srcs);

    // E: gather v5.2 (srcs prefetch-ahead)
    gather_kernel<<<ND / 32, 256, 0, stream>>>(cnt, off, srcs, h0, h1, h2,
        o_as00, o_ad00, o_as10, o_ad10, o_as11, o_ad11, o_as21, o_ad21, agg);

    // F: semantic v7 (full-depth prefetch, (256,4), grid 1024)
    semantic_kernel<<<1024, 256, 0, stream>>>(agg, kwf8, kb, q, lb,
                                              colsum2, score, done, out);
}